// Round 1
// baseline (11195.715 us; speedup 1.0000x reference)
//
#include <hip/hip_runtime.h>
#include <stdint.h>

// Window MHA fused kernel, fp32 baseline.
// Shapes: 4096 windows x (L=49 tokens, EMB=384), 12 heads x 32.
// One block per window, 512 threads, ~146KB dynamic LDS.

#define LTOK 49
#define EMB 384
#define NH 12
#define HD 32
#define SCALE 0.17677669529663687f  // 1/sqrt(32)

// LDS strides chosen for bank-conflict freedom + vector alignment:
#define XS_STRIDE 386   // f32; word-stride%32==2 -> 2-way (free), float2-aligned
#define QKV_STRIDE 36   // f32; rows 144B -> float4-aligned
#define S_STRIDE 52     // f32
#define CTX_STRIDE 396  // bf16; byte-stride 792 -> short4(8B)-aligned, 2-way banks

#define XS_OFF 0
#define XS_BYTES (LTOK * XS_STRIDE * 4)          // 75656 -> pad to 75664 (16B)
#define QKV_OFF 75664
#define QKV_BYTES (3 * LTOK * QKV_STRIDE * 4)    // 21168
#define S_OFF (QKV_OFF + QKV_BYTES)              // 96832
#define S_BYTES (LTOK * S_STRIDE * 4)            // 10192
#define CTX_OFF (S_OFF + S_BYTES)                // 107024
#define CTX_BYTES (LTOK * CTX_STRIDE * 2)        // 38808
#define SMEM_TOTAL (CTX_OFF + CTX_BYTES)         // 145832 <= 163840

__device__ __forceinline__ unsigned short f2bf(float f) {
    union { float f; unsigned int u; } v; v.f = f;
    unsigned int r = (v.u + 0x7FFFu + ((v.u >> 16) & 1u)) >> 16;  // RNE
    return (unsigned short)r;
}
__device__ __forceinline__ float bf2f(unsigned short b) {
    union { unsigned int u; float f; } v; v.u = ((unsigned int)b) << 16;
    return v.f;
}

// Setup: transpose w_qkv (384x1152 -> 1152x384), w_out (384x384 -> 384x384),
// and pre-gather relative-position bias to (12,49,49).
__global__ __launch_bounds__(256) void setup_k(
    const float* __restrict__ wqkv, const float* __restrict__ wout,
    const float* __restrict__ table, const int* __restrict__ relidx,
    float* __restrict__ wt_qkv, float* __restrict__ wt_out,
    float* __restrict__ bias_m)
{
    int idx = blockIdx.x * 256 + threadIdx.x;
    if (idx < 384 * 1152) {
        int k = idx / 1152, c = idx % 1152;
        wt_qkv[c * 384 + k] = wqkv[idx];
    } else if (idx < 384 * 1152 + 384 * 384) {
        int t = idx - 384 * 1152;
        int k = t / 384, c = t % 384;
        wt_out[c * 384 + k] = wout[t];
    } else if (idx < 384 * 1152 + 384 * 384 + 12 * 2401) {
        int t = idx - (384 * 1152 + 384 * 384);
        int h = t / 2401, ij = t % 2401;
        bias_m[h * 2401 + ij] = table[relidx[ij] * 12 + h];
    }
}

__global__ __launch_bounds__(512) void wmha_fused(
    const float* __restrict__ x, const float* __restrict__ mask,
    const float* __restrict__ b_qkv, const float* __restrict__ b_out,
    const float* __restrict__ wt_qkv, const float* __restrict__ wt_out,
    const float* __restrict__ bias_m, float* __restrict__ out)
{
    extern __shared__ __align__(16) char smem[];
    float* Xs = (float*)(smem + XS_OFF);
    float* QKVs = (float*)(smem + QKV_OFF);
    float* Ss = (float*)(smem + S_OFF);
    unsigned short* ctx = (unsigned short*)(smem + CTX_OFF);

    const int tid = threadIdx.x;
    const int lane = tid & 63;
    const int wv = __builtin_amdgcn_readfirstlane(tid >> 6);  // wave id 0..7 (uniform)
    const int win = blockIdx.x;
    const int wi = win & 63;  // window index within NW=64 (for mask)

    // ---- Phase 0: stage X window (49x384 f32) into LDS ----
    const float* xw = x + (size_t)win * (LTOK * EMB);
    for (int i2 = tid; i2 < (LTOK * EMB) / 2; i2 += 512) {
        int e = i2 * 2;
        int r = e / EMB, k = e % EMB;
        float2 v = *(const float2*)(xw + e);
        *(float2*)&Xs[r * XS_STRIDE + k] = v;
    }
    __syncthreads();

    const int r = (lane < 48) ? lane : 48;  // lanes 49..63 shadow row 48 (stores predicated)
    const bool act = (lane < 49);

    // ---- Per-head: QKV gemm -> scores -> softmax -> A@V ----
    for (int h = 0; h < NH; ++h) {
        // QKV: 49 rows x 96 cols, K=384. lane->row, wave->12-col strip.
        float acc[12];
        int wcol[12];
        #pragma unroll
        for (int c = 0; c < 12; ++c) {
            acc[c] = 0.f;
            int cc = wv * 12 + c;          // 0..95
            int which = cc >> 5;           // 0=q 1=k 2=v
            wcol[c] = which * EMB + h * HD + (cc & 31);  // column in w_qkv
        }
        for (int k0 = 0; k0 < EMB; k0 += 8) {
            float xv[8];
            #pragma unroll
            for (int j = 0; j < 4; ++j) {
                float2 t = *(const float2*)&Xs[r * XS_STRIDE + k0 + 2 * j];
                xv[2 * j] = t.x; xv[2 * j + 1] = t.y;
            }
            #pragma unroll
            for (int c = 0; c < 12; ++c) {
                const float* wp = wt_qkv + wcol[c] * EMB + k0;  // wave-uniform -> s_load
                float4 w0 = *(const float4*)wp;
                float4 w1 = *(const float4*)(wp + 4);
                acc[c] = fmaf(xv[0], w0.x, acc[c]);
                acc[c] = fmaf(xv[1], w0.y, acc[c]);
                acc[c] = fmaf(xv[2], w0.z, acc[c]);
                acc[c] = fmaf(xv[3], w0.w, acc[c]);
                acc[c] = fmaf(xv[4], w1.x, acc[c]);
                acc[c] = fmaf(xv[5], w1.y, acc[c]);
                acc[c] = fmaf(xv[6], w1.z, acc[c]);
                acc[c] = fmaf(xv[7], w1.w, acc[c]);
            }
        }
        if (act) {
            #pragma unroll
            for (int c = 0; c < 12; ++c) {
                int cc = wv * 12 + c;
                int which = cc >> 5;
                QKVs[(which * LTOK + r) * QKV_STRIDE + (cc & 31)] = acc[c] + b_qkv[wcol[c]];
            }
        }
        __syncthreads();

        // Scores: S[i][j] = scale*q_i.k_j + bias + mask
        for (int idx = tid; idx < LTOK * LTOK; idx += 512) {
            int i = idx / 49, j = idx % 49;
            const float* qp = &QKVs[i * QKV_STRIDE];
            const float* kp = &QKVs[(LTOK + j) * QKV_STRIDE];
            float s = 0.f;
            #pragma unroll
            for (int d = 0; d < HD; d += 4) {
                float4 qv = *(const float4*)(qp + d);
                float4 kv = *(const float4*)(kp + d);
                s = fmaf(qv.x, kv.x, s); s = fmaf(qv.y, kv.y, s);
                s = fmaf(qv.z, kv.z, s); s = fmaf(qv.w, kv.w, s);
            }
            Ss[i * S_STRIDE + j] = s * SCALE + bias_m[h * 2401 + idx] + mask[wi * 2401 + idx];
        }
        __syncthreads();

        // Softmax: one thread per row (tiny)
        if (tid < 49) {
            float mx = -1e30f;
            for (int j = 0; j < 49; ++j) mx = fmaxf(mx, Ss[tid * S_STRIDE + j]);
            float sum = 0.f;
            for (int j = 0; j < 49; ++j) {
                float e = __expf(Ss[tid * S_STRIDE + j] - mx);
                Ss[tid * S_STRIDE + j] = e; sum += e;
            }
            float inv = 1.f / sum;
            for (int j = 0; j < 49; ++j) Ss[tid * S_STRIDE + j] *= inv;
        }
        __syncthreads();

        // Context: C = A @ V, write bf16 into ctx[l][h*32+d]
        for (int idx = tid; idx < LTOK * 8; idx += 512) {
            int i = idx >> 3, dq = (idx & 7) << 2;
            float4 a = {0.f, 0.f, 0.f, 0.f};
            for (int j = 0; j < 49; ++j) {
                float al = Ss[i * S_STRIDE + j];
                float4 v = *(const float4*)&QKVs[(2 * LTOK + j) * QKV_STRIDE + dq];
                a.x = fmaf(al, v.x, a.x); a.y = fmaf(al, v.y, a.y);
                a.z = fmaf(al, v.z, a.z); a.w = fmaf(al, v.w, a.w);
            }
            int cb = i * CTX_STRIDE + h * HD + dq;
            ctx[cb + 0] = f2bf(a.x); ctx[cb + 1] = f2bf(a.y);
            ctx[cb + 2] = f2bf(a.z); ctx[cb + 3] = f2bf(a.w);
        }
        __syncthreads();
    }

    // ---- Phase 3: out = ctx(49x384) @ w_out(384x384) + b_out ----
    const int c1 = wv * 48;  // this wave's 48-col strip
    for (int cb = 0; cb < 6; ++cb) {
        float acc[8];
        #pragma unroll
        for (int c = 0; c < 8; ++c) acc[c] = 0.f;
        for (int k0 = 0; k0 < EMB; k0 += 8) {
            float xv[8];
            short4 s0 = *(const short4*)&ctx[r * CTX_STRIDE + k0];
            short4 s1 = *(const short4*)&ctx[r * CTX_STRIDE + k0 + 4];
            xv[0] = bf2f((unsigned short)s0.x); xv[1] = bf2f((unsigned short)s0.y);
            xv[2] = bf2f((unsigned short)s0.z); xv[3] = bf2f((unsigned short)s0.w);
            xv[4] = bf2f((unsigned short)s1.x); xv[5] = bf2f((unsigned short)s1.y);
            xv[6] = bf2f((unsigned short)s1.z); xv[7] = bf2f((unsigned short)s1.w);
            #pragma unroll
            for (int c = 0; c < 8; ++c) {
                const float* wp = wt_out + (c1 + cb * 8 + c) * EMB + k0;  // uniform
                float4 w0 = *(const float4*)wp;
                float4 w1 = *(const float4*)(wp + 4);
                acc[c] = fmaf(xv[0], w0.x, acc[c]);
                acc[c] = fmaf(xv[1], w0.y, acc[c]);
                acc[c] = fmaf(xv[2], w0.z, acc[c]);
                acc[c] = fmaf(xv[3], w0.w, acc[c]);
                acc[c] = fmaf(xv[4], w1.x, acc[c]);
                acc[c] = fmaf(xv[5], w1.y, acc[c]);
                acc[c] = fmaf(xv[6], w1.z, acc[c]);
                acc[c] = fmaf(xv[7], w1.w, acc[c]);
            }
        }
        if (act) {
            size_t gb = ((size_t)win * LTOK + r) * EMB + c1 + cb * 8;
            #pragma unroll
            for (int c = 0; c < 8; ++c) out[gb + c] = acc[c] + b_out[c1 + cb * 8 + c];
        }
    }
}

extern "C" void kernel_launch(void* const* d_in, const int* in_sizes, int n_in,
                              void* d_out, int out_size, void* d_ws, size_t ws_size,
                              hipStream_t stream)
{
    const float* x      = (const float*)d_in[0];
    const float* mask   = (const float*)d_in[1];
    const float* w_qkv  = (const float*)d_in[2];
    const float* b_qkv  = (const float*)d_in[3];
    const float* w_out  = (const float*)d_in[4];
    const float* b_out  = (const float*)d_in[5];
    const float* table  = (const float*)d_in[6];
    const int*   relidx = (const int*)d_in[7];
    float* out = (float*)d_out;

    float* wt_qkv = (float*)d_ws;                 // 1152x384
    float* wt_out = wt_qkv + 384 * 1152;          // 384x384
    float* bias_m = wt_out + 384 * 384;           // 12x49x49
    size_t need = (size_t)(384 * 1152 + 384 * 384 + 12 * 2401) * 4;
    if (ws_size < need) return;

    int total = 384 * 1152 + 384 * 384 + 12 * 2401;
    setup_k<<<(total + 255) / 256, 256, 0, stream>>>(w_qkv, w_out, table, relidx,
                                                     wt_qkv, wt_out, bias_m);

    // >64KB dynamic LDS opt-in (idempotent; not a stream op, graph-capture safe)
    hipFuncSetAttribute(reinterpret_cast<const void*>(wmha_fused),
                        hipFuncAttributeMaxDynamicSharedMemorySize, SMEM_TOTAL);
    wmha_fused<<<4096, 512, SMEM_TOTAL, stream>>>(x, mask, b_qkv, b_out,
                                                  wt_qkv, wt_out, bias_m, out);
}